// Round 8
// baseline (684.441 us; speedup 1.0000x reference)
//
#include <hip/hip_runtime.h>
#include <hip/hip_bf16.h>
#include <math.h>

#define S_DIM 2048
#define B_DIM 64
#define F_DIM 512
#define NCHUNK 120   // 64*120*2048B = 15.0 MB partials + 1KB counters <= 16MB ws
// output: (B, 3*F) = [last, mean, max]

__device__ __forceinline__ ushort bf16_bits(float v) {
    __hip_bfloat16 h = __float2bfloat16(v);   // round-to-nearest
    return *reinterpret_cast<ushort*>(&h);
}
__device__ __forceinline__ float bf16_val(ushort u) {
    __hip_bfloat16 h = *reinterpret_cast<__hip_bfloat16*>(&u);
    return __bfloat162float(h);
}

// Fused: per (chunk, batch) partial sum/max over interleaved rows
// s = c + NCHUNK*j, bf16 partial to ws, then release protocol:
//   all threads store -> each thread __threadfence() -> __syncthreads()
//   -> tid0 atomicAdd arrival counter.
// (Round 6/7 bug: no __syncthreads() before the atomic, so tid0 counted
//  arrival while wave 1's stores were still unissued -> finalizer read
//  incomplete partials.)
// The LAST arriver re-reads the batch's partials in fixed order
// (deterministic) and writes [last, mean, max].
__global__ __launch_bounds__(128) void scp_fused(const float* __restrict__ x,
                                                 const int* __restrict__ lengths,
                                                 ushort* __restrict__ part,
                                                 unsigned int* __restrict__ cnt,
                                                 float* __restrict__ out) {
    const int c = blockIdx.x;           // chunk (fast dim: CU sees many batches)
    const int b = blockIdx.y;           // batch
    const int tid = threadIdx.x;
    const int f = tid * 4;              // 128 threads x float4 = 512 floats
    const int len = lengths[b];

    float4 sum = make_float4(0.f, 0.f, 0.f, 0.f);
    float4 mx = make_float4(-INFINITY, -INFINITY, -INFINITY, -INFINITY);

    const size_t row_stride = (size_t)B_DIM * F_DIM;
    const float* p = x + (size_t)c * row_stride + (size_t)b * F_DIM + f;
    const size_t step = (size_t)NCHUNK * row_stride;

    const int nj = (len > c) ? ((len - c + NCHUNK - 1) / NCHUNK) : 0;

    #pragma unroll 4
    for (int j = 0; j < nj; ++j) {
        float4 v = *reinterpret_cast<const float4*>(p);
        sum.x += v.x; sum.y += v.y; sum.z += v.z; sum.w += v.w;
        mx.x = fmaxf(mx.x, v.x);
        mx.y = fmaxf(mx.y, v.y);
        mx.z = fmaxf(mx.z, v.z);
        mx.w = fmaxf(mx.w, v.w);
        p += step;
    }

    if (nj > 0) {   // empty chunks (c >= len) write nothing; combine skips them
        ushort* dst = part + ((size_t)b * NCHUNK + c) * (2 * F_DIM);
        ushort4 us, um;
        us.x = bf16_bits(sum.x); us.y = bf16_bits(sum.y);
        us.z = bf16_bits(sum.z); us.w = bf16_bits(sum.w);
        um.x = bf16_bits(mx.x);  um.y = bf16_bits(mx.y);
        um.z = bf16_bits(mx.z);  um.w = bf16_bits(mx.w);
        *reinterpret_cast<ushort4*>(dst + f) = us;
        *reinterpret_cast<ushort4*>(dst + F_DIM + f) = um;
    }

    // ---- release: every thread fences its stores, THEN barrier, THEN count
    __threadfence();
    __syncthreads();                    // all 128 threads' stores fenced first
    __shared__ int is_last;
    if (tid == 0) {
        unsigned int old = __hip_atomic_fetch_add(&cnt[b], 1u,
                                                  __ATOMIC_ACQ_REL,
                                                  __HIP_MEMORY_SCOPE_AGENT);
        is_last = (old == NCHUNK - 1);
    }
    __syncthreads();
    if (!is_last) return;
    __threadfence();   // acquire: see all other blocks' partial stores

    // ---- finalize batch b (one block, fixed-order combine -> deterministic)
    sum = make_float4(0.f, 0.f, 0.f, 0.f);
    mx = make_float4(-INFINITY, -INFINITY, -INFINITY, -INFINITY);

    const int ncc = (len < NCHUNK) ? len : NCHUNK;
    #pragma unroll 8
    for (int cc = 0; cc < ncc; ++cc) {
        const ushort* src = part + ((size_t)b * NCHUNK + cc) * (2 * F_DIM);
        ushort4 s4 = *reinterpret_cast<const ushort4*>(src + f);
        ushort4 m4 = *reinterpret_cast<const ushort4*>(src + F_DIM + f);
        sum.x += bf16_val(s4.x); sum.y += bf16_val(s4.y);
        sum.z += bf16_val(s4.z); sum.w += bf16_val(s4.w);
        mx.x = fmaxf(mx.x, bf16_val(m4.x));
        mx.y = fmaxf(mx.y, bf16_val(m4.y));
        mx.z = fmaxf(mx.z, bf16_val(m4.z));
        mx.w = fmaxf(mx.w, bf16_val(m4.w));
    }

    const float4 lastv = *reinterpret_cast<const float4*>(
        x + ((size_t)(len - 1) * B_DIM + b) * F_DIM + f);
    const float inv = 1.0f / (float)len;

    float* ob = out + (size_t)b * (3 * F_DIM);
    *reinterpret_cast<float4*>(ob + f) = lastv;
    *reinterpret_cast<float4*>(ob + F_DIM + f) =
        make_float4(sum.x * inv, sum.y * inv, sum.z * inv, sum.w * inv);
    *reinterpret_cast<float4*>(ob + 2 * F_DIM + f) = mx;
}

extern "C" void kernel_launch(void* const* d_in, const int* in_sizes, int n_in,
                              void* d_out, int out_size, void* d_ws, size_t ws_size,
                              hipStream_t stream) {
    const float* x = (const float*)d_in[0];
    const int* lengths = (const int*)d_in[1];
    float* out = (float*)d_out;

    // ws layout: [0,1024) per-batch arrival counters (zeroed every call;
    // harness poisons ws once and never re-poisons), partials at +1024:
    // 64*120*2048B = 15,728,640 B; total 15,729,664 <= 16MB.
    unsigned int* cnt = (unsigned int*)d_ws;
    ushort* part = (ushort*)((char*)d_ws + 1024);

    hipMemsetAsync(d_ws, 0, 1024, stream);
    scp_fused<<<dim3(NCHUNK, B_DIM), 128, 0, stream>>>(x, lengths, part, cnt, out);
}

// Round 9
// 34.333 us; speedup vs baseline: 19.9352x; 19.9352x over previous
//
#include <hip/hip_runtime.h>
#include <hip/hip_bf16.h>
#include <math.h>

#define S_DIM 2048
#define B_DIM 64
#define F_DIM 512
#define NCHUNK 128   // 64*128*2048B = 16MB partials, exactly ws (no counters now)
// output: (B, 3*F) = [last, mean, max]
// NOTE (R8 lesson): no device-scope fences/single-kernel fan-in — per-XCD L2
// non-coherence makes agent-scope release fences (L2 writeback) cost ~900us
// across 8k blocks. Two plain kernels it is.

__device__ __forceinline__ ushort bf16_bits(float v) {
    __hip_bfloat16 h = __float2bfloat16(v);   // round-to-nearest
    return *reinterpret_cast<ushort*>(&h);
}
__device__ __forceinline__ float bf16_val(ushort u) {
    __hip_bfloat16 h = *reinterpret_cast<__hip_bfloat16*>(&u);
    return __bfloat162float(h);
}

// Kernel 1: per (chunk, batch) partial sum + max over INTERLEAVED rows
// s = c + NCHUNK*j. Grid (x=chunk, y=batch): a CU's resident blocks share c
// but span 16 distinct batches -> CU work decorrelated from batch length.
// 8192 blocks = 2x residency -> HW refill load-balances the tail.
// Empty chunks (c >= len) write nothing and exit (kernel 2 bounds its read
// at min(len, NCHUNK)).
__global__ __launch_bounds__(128) void scp_partial(const float* __restrict__ x,
                                                   const int* __restrict__ lengths,
                                                   ushort* __restrict__ ws) {
    const int c = blockIdx.x;           // chunk (fast dim)
    const int b = blockIdx.y;           // batch
    const int f = threadIdx.x * 4;      // 128 threads x float4 = 512 floats
    const int len = lengths[b];

    const int nj = (len > c) ? ((len - c + NCHUNK - 1) >> 7) : 0;
    if (nj == 0) return;

    float4 sum = make_float4(0.f, 0.f, 0.f, 0.f);
    float4 mx = make_float4(-INFINITY, -INFINITY, -INFINITY, -INFINITY);

    const size_t row_stride = (size_t)B_DIM * F_DIM;
    const float* p = x + (size_t)c * row_stride + (size_t)b * F_DIM + f;
    const size_t step = (size_t)NCHUNK * row_stride;

    #pragma unroll 4
    for (int j = 0; j < nj; ++j) {
        float4 v = *reinterpret_cast<const float4*>(p);
        sum.x += v.x; sum.y += v.y; sum.z += v.z; sum.w += v.w;
        mx.x = fmaxf(mx.x, v.x);
        mx.y = fmaxf(mx.y, v.y);
        mx.z = fmaxf(mx.z, v.z);
        mx.w = fmaxf(mx.w, v.w);
        p += step;
    }

    // layout per (b,c): [0,512) bf16 sums, [512,1024) bf16 maxes (ushort units)
    ushort* dst = ws + ((size_t)b * NCHUNK + c) * (2 * F_DIM);
    ushort4 us, um;
    us.x = bf16_bits(sum.x); us.y = bf16_bits(sum.y);
    us.z = bf16_bits(sum.z); us.w = bf16_bits(sum.w);
    um.x = bf16_bits(mx.x);  um.y = bf16_bits(mx.y);
    um.z = bf16_bits(mx.z);  um.w = bf16_bits(mx.w);
    *reinterpret_cast<ushort4*>(dst + f) = us;
    *reinterpret_cast<ushort4*>(dst + F_DIM + f) = um;
}

// Kernel 2: combine chunk partials (8-way chunk-parallel + LDS reduce), fetch
// last row, write [last, mean, max]. Grid (B, 4) x 256 threads: block (b,y)
// owns features [y*128, (y+1)*128); tid = 32 float4-groups x 8 chunk lanes.
__global__ __launch_bounds__(256) void scp_finalize(const float* __restrict__ x,
                                                    const int* __restrict__ lengths,
                                                    const ushort* __restrict__ ws,
                                                    float* __restrict__ out) {
    const int b = blockIdx.x;
    const int y = blockIdx.y;           // feature quarter
    const int tid = threadIdx.x;
    const int f4l = tid & 31;           // 32 float4 groups = 128 floats
    const int cpar = tid >> 5;          // 0..7 chunk-split lane
    const int f = y * 128 + f4l * 4;
    const int len = lengths[b];
    const int ncc = (len < NCHUNK) ? len : NCHUNK;  // only written tiles

    // issue last-row load early; latency hides under partial reads
    const float4 last = *reinterpret_cast<const float4*>(
        x + ((size_t)(len - 1) * B_DIM + b) * F_DIM + f);

    float4 sum = make_float4(0.f, 0.f, 0.f, 0.f);
    float4 mx = make_float4(-INFINITY, -INFINITY, -INFINITY, -INFINITY);

    for (int c = cpar; c < ncc; c += 8) {
        const ushort* src = ws + ((size_t)b * NCHUNK + c) * (2 * F_DIM);
        ushort4 s4 = *reinterpret_cast<const ushort4*>(src + f);
        ushort4 m4 = *reinterpret_cast<const ushort4*>(src + F_DIM + f);
        sum.x += bf16_val(s4.x); sum.y += bf16_val(s4.y);
        sum.z += bf16_val(s4.z); sum.w += bf16_val(s4.w);
        mx.x = fmaxf(mx.x, bf16_val(m4.x));
        mx.y = fmaxf(mx.y, bf16_val(m4.y));
        mx.z = fmaxf(mx.z, bf16_val(m4.z));
        mx.w = fmaxf(mx.w, bf16_val(m4.w));
    }

    __shared__ float4 ssum[8][32];
    __shared__ float4 smax[8][32];
    ssum[cpar][f4l] = sum;
    smax[cpar][f4l] = mx;
    __syncthreads();

    if (cpar == 0) {
        #pragma unroll
        for (int k = 1; k < 8; ++k) {
            float4 s4 = ssum[k][f4l];
            float4 m4 = smax[k][f4l];
            sum.x += s4.x; sum.y += s4.y; sum.z += s4.z; sum.w += s4.w;
            mx.x = fmaxf(mx.x, m4.x);
            mx.y = fmaxf(mx.y, m4.y);
            mx.z = fmaxf(mx.z, m4.z);
            mx.w = fmaxf(mx.w, m4.w);
        }

        const float inv = 1.0f / (float)len;
        float4 mean = make_float4(sum.x * inv, sum.y * inv, sum.z * inv, sum.w * inv);

        float* ob = out + (size_t)b * (3 * F_DIM);
        *reinterpret_cast<float4*>(ob + f) = last;
        *reinterpret_cast<float4*>(ob + F_DIM + f) = mean;
        *reinterpret_cast<float4*>(ob + 2 * F_DIM + f) = mx;
    }
}

extern "C" void kernel_launch(void* const* d_in, const int* in_sizes, int n_in,
                              void* d_out, int out_size, void* d_ws, size_t ws_size,
                              hipStream_t stream) {
    const float* x = (const float*)d_in[0];
    const int* lengths = (const int*)d_in[1];
    float* out = (float*)d_out;
    ushort* ws = (ushort*)d_ws;

    scp_partial<<<dim3(NCHUNK, B_DIM), 128, 0, stream>>>(x, lengths, ws);
    scp_finalize<<<dim3(B_DIM, 4), 256, 0, stream>>>(x, lengths, ws, out);
}

// Round 10
// 32.526 us; speedup vs baseline: 21.0430x; 1.0556x over previous
//
#include <hip/hip_runtime.h>
#include <hip/hip_bf16.h>
#include <math.h>

#define S_DIM 2048
#define B_DIM 64
#define F_DIM 512
#define NCHUNK 128   // 8192 blocks = 2x residency -> HW refill load-balances
// output: (B, 3*F) = [last, mean, max]
// R8 lesson: no cross-block fan-in — agent-scope fences cost ~900us on 8k
// blocks (per-XCD L2 writeback). Two plain kernels.
// R8 counters: d_ws is ~1GB (fill writes 1GB), FETCH ~71MB << 134MB touched
// -> x is ~half L3-resident during replays.

__device__ __forceinline__ ushort bf16_bits(float v) {
    __hip_bfloat16 h = __float2bfloat16(v);   // round-to-nearest
    return *reinterpret_cast<ushort*>(&h);
}
__device__ __forceinline__ float bf16_val(ushort u) {
    __hip_bfloat16 h = *reinterpret_cast<__hip_bfloat16*>(&u);
    return __bfloat162float(h);
}

// Kernel 1: per (chunk, batch) partial sum + max over interleaved rows
// s = c + NCHUNK*j. Grid (x=chunk, y=batch) decorrelates CU work from batch
// length. The block whose chunk contains row len-1 (c == (len-1)&127) loads
// it as its LAST iteration and writes out[b][0:512] directly -> kernel 2
// never reads x.
__global__ __launch_bounds__(128) void scp_partial(const float* __restrict__ x,
                                                   const int* __restrict__ lengths,
                                                   ushort* __restrict__ ws,
                                                   float* __restrict__ out) {
    const int c = blockIdx.x;           // chunk (fast dim)
    const int b = blockIdx.y;           // batch
    const int f = threadIdx.x * 4;      // 128 threads x float4 = 512 floats
    const int len = lengths[b];

    const int nj = (len > c) ? ((len - c + NCHUNK - 1) >> 7) : 0;
    if (nj == 0) return;

    float4 sum = make_float4(0.f, 0.f, 0.f, 0.f);
    float4 mx = make_float4(-INFINITY, -INFINITY, -INFINITY, -INFINITY);
    float4 v  = make_float4(0.f, 0.f, 0.f, 0.f);

    const size_t row_stride = (size_t)B_DIM * F_DIM;
    const float* p = x + (size_t)c * row_stride + (size_t)b * F_DIM + f;
    const size_t step = (size_t)NCHUNK * row_stride;

    #pragma unroll 4
    for (int j = 0; j < nj; ++j) {
        v = *reinterpret_cast<const float4*>(p);
        sum.x += v.x; sum.y += v.y; sum.z += v.z; sum.w += v.w;
        mx.x = fmaxf(mx.x, v.x);
        mx.y = fmaxf(mx.y, v.y);
        mx.z = fmaxf(mx.z, v.z);
        mx.w = fmaxf(mx.w, v.w);
        p += step;
    }

    // last-row chunk: final iteration's v IS row len-1 -> write 'last' output
    if (c == ((len - 1) & (NCHUNK - 1))) {
        *reinterpret_cast<float4*>(out + (size_t)b * (3 * F_DIM) + f) = v;
    }

    // layout per (b,c): [0,512) bf16 sums, [512,1024) bf16 maxes (ushort units)
    ushort* dst = ws + ((size_t)b * NCHUNK + c) * (2 * F_DIM);
    ushort4 us, um;
    us.x = bf16_bits(sum.x); us.y = bf16_bits(sum.y);
    us.z = bf16_bits(sum.z); us.w = bf16_bits(sum.w);
    um.x = bf16_bits(mx.x);  um.y = bf16_bits(mx.y);
    um.z = bf16_bits(mx.z);  um.w = bf16_bits(mx.w);
    *reinterpret_cast<ushort4*>(dst + f) = us;
    *reinterpret_cast<ushort4*>(dst + F_DIM + f) = um;
}

// Kernel 2: combine chunk partials. Grid (B, 8) x 256 threads: block (b,y)
// owns 64 features [y*64, (y+1)*64); tid = 16 float4-groups x 16 chunk lanes
// -> 8 load iterations, then log2 LDS tree. No x reads (last done in K1).
__global__ __launch_bounds__(256) void scp_finalize(const int* __restrict__ lengths,
                                                    const ushort* __restrict__ ws,
                                                    float* __restrict__ out) {
    const int b = blockIdx.x;
    const int y = blockIdx.y;           // feature 1/8th
    const int tid = threadIdx.x;
    const int f4l = tid & 15;           // 16 float4 groups = 64 floats
    const int cpar = tid >> 4;          // 0..15 chunk-split lane
    const int f = y * 64 + f4l * 4;
    const int len = lengths[b];
    const int ncc = (len < NCHUNK) ? len : NCHUNK;  // only written tiles

    float4 sum = make_float4(0.f, 0.f, 0.f, 0.f);
    float4 mx = make_float4(-INFINITY, -INFINITY, -INFINITY, -INFINITY);

    for (int c = cpar; c < ncc; c += 16) {
        const ushort* src = ws + ((size_t)b * NCHUNK + c) * (2 * F_DIM);
        ushort4 s4 = *reinterpret_cast<const ushort4*>(src + f);
        ushort4 m4 = *reinterpret_cast<const ushort4*>(src + F_DIM + f);
        sum.x += bf16_val(s4.x); sum.y += bf16_val(s4.y);
        sum.z += bf16_val(s4.z); sum.w += bf16_val(s4.w);
        mx.x = fmaxf(mx.x, bf16_val(m4.x));
        mx.y = fmaxf(mx.y, bf16_val(m4.y));
        mx.z = fmaxf(mx.z, bf16_val(m4.z));
        mx.w = fmaxf(mx.w, bf16_val(m4.w));
    }

    __shared__ float4 ssum[16][16];
    __shared__ float4 smax[16][16];
    ssum[cpar][f4l] = sum;
    smax[cpar][f4l] = mx;
    __syncthreads();

    // tree reduce over cpar: 16 -> 8 -> 4 -> 2 -> 1
    #pragma unroll
    for (int h = 8; h >= 1; h >>= 1) {
        if (cpar < h) {
            float4 s4 = ssum[cpar + h][f4l];
            float4 m4 = smax[cpar + h][f4l];
            float4 a = ssum[cpar][f4l];
            float4 m = smax[cpar][f4l];
            a.x += s4.x; a.y += s4.y; a.z += s4.z; a.w += s4.w;
            m.x = fmaxf(m.x, m4.x);
            m.y = fmaxf(m.y, m4.y);
            m.z = fmaxf(m.z, m4.z);
            m.w = fmaxf(m.w, m4.w);
            ssum[cpar][f4l] = a;
            smax[cpar][f4l] = m;
        }
        __syncthreads();
    }

    if (cpar == 0) {
        float4 a = ssum[0][f4l];
        float4 m = smax[0][f4l];
        const float inv = 1.0f / (float)len;
        float* ob = out + (size_t)b * (3 * F_DIM);
        *reinterpret_cast<float4*>(ob + F_DIM + f) =
            make_float4(a.x * inv, a.y * inv, a.z * inv, a.w * inv);
        *reinterpret_cast<float4*>(ob + 2 * F_DIM + f) = m;
    }
}

extern "C" void kernel_launch(void* const* d_in, const int* in_sizes, int n_in,
                              void* d_out, int out_size, void* d_ws, size_t ws_size,
                              hipStream_t stream) {
    const float* x = (const float*)d_in[0];
    const int* lengths = (const int*)d_in[1];
    float* out = (float*)d_out;
    ushort* ws = (ushort*)d_ws;

    scp_partial<<<dim3(NCHUNK, B_DIM), 128, 0, stream>>>(x, lengths, ws, out);
    scp_finalize<<<dim3(B_DIM, 8), 256, 0, stream>>>(lengths, ws, out);
}

// Round 11
// 32.227 us; speedup vs baseline: 21.2379x; 1.0093x over previous
//
#include <hip/hip_runtime.h>
#include <hip/hip_bf16.h>
#include <math.h>

#define S_DIM 2048
#define B_DIM 64
#define F_DIM 512
#define NCHUNK 96    // 6144 blocks = 1.5x residency (refill-balanced), 12MB partials
// output: (B, 3*F) = [last, mean, max]
// R8 lesson: no cross-block fan-in — agent-scope fences cost ~900us on 8k
// blocks (per-XCD L2 writeback). Two plain kernels.

typedef ushort ushort8v __attribute__((ext_vector_type(8)));

__device__ __forceinline__ ushort bf16_bits(float v) {
    __hip_bfloat16 h = __float2bfloat16(v);   // round-to-nearest
    return *reinterpret_cast<ushort*>(&h);
}
__device__ __forceinline__ float bf16_val(ushort u) {
    __hip_bfloat16 h = *reinterpret_cast<__hip_bfloat16*>(&u);
    return __bfloat162float(h);
}

// Kernel 1: per (chunk, batch) partial sum + max over interleaved rows
// s = c + NCHUNK*j. Grid (x=chunk, y=batch) keeps a CU's resident blocks on
// 16 distinct batches. The block whose chunk contains row len-1 writes the
// 'last' output directly (its final iteration loaded that row).
__global__ __launch_bounds__(128) void scp_partial(const float* __restrict__ x,
                                                   const int* __restrict__ lengths,
                                                   ushort* __restrict__ ws,
                                                   float* __restrict__ out) {
    const int c = blockIdx.x;           // chunk (fast dim)
    const int b = blockIdx.y;           // batch
    const int f = threadIdx.x * 4;      // 128 threads x float4 = 512 floats
    const int len = lengths[b];

    const int nj = (len > c) ? ((len - c + NCHUNK - 1) / NCHUNK) : 0;
    if (nj == 0) return;

    float4 sum = make_float4(0.f, 0.f, 0.f, 0.f);
    float4 mx = make_float4(-INFINITY, -INFINITY, -INFINITY, -INFINITY);
    float4 v  = make_float4(0.f, 0.f, 0.f, 0.f);

    const size_t row_stride = (size_t)B_DIM * F_DIM;
    const float* p = x + (size_t)c * row_stride + (size_t)b * F_DIM + f;
    const size_t step = (size_t)NCHUNK * row_stride;

    #pragma unroll 4
    for (int j = 0; j < nj; ++j) {
        v = *reinterpret_cast<const float4*>(p);
        sum.x += v.x; sum.y += v.y; sum.z += v.z; sum.w += v.w;
        mx.x = fmaxf(mx.x, v.x);
        mx.y = fmaxf(mx.y, v.y);
        mx.z = fmaxf(mx.z, v.z);
        mx.w = fmaxf(mx.w, v.w);
        p += step;
    }

    // last-row chunk: final iteration's v IS row len-1 -> write 'last' output
    if (c == (len - 1) % NCHUNK) {
        *reinterpret_cast<float4*>(out + (size_t)b * (3 * F_DIM) + f) = v;
    }

    // layout per (b,c): [0,512) bf16 sums, [512,1024) bf16 maxes (ushort units)
    ushort* dst = ws + ((size_t)b * NCHUNK + c) * (2 * F_DIM);
    ushort4 us, um;
    us.x = bf16_bits(sum.x); us.y = bf16_bits(sum.y);
    us.z = bf16_bits(sum.z); us.w = bf16_bits(sum.w);
    um.x = bf16_bits(mx.x);  um.y = bf16_bits(mx.y);
    um.z = bf16_bits(mx.z);  um.w = bf16_bits(mx.w);
    *reinterpret_cast<ushort4*>(dst + f) = us;
    *reinterpret_cast<ushort4*>(dst + F_DIM + f) = um;
}

// Kernel 2: combine chunk partials, role-split wide loads.
// Grid (B, 8) x 256: block (b,y) owns 64 features. Thread = (fgrp 0..7 x
// 8 features, role 0=sum/1=max, ctile 0..15). One 16B ushort8 load per
// iteration, 6 iterations (ncc<=96), then 16-way LDS tree per role.
__global__ __launch_bounds__(256) void scp_finalize(const int* __restrict__ lengths,
                                                    const ushort* __restrict__ ws,
                                                    float* __restrict__ out) {
    const int b = blockIdx.x;
    const int y = blockIdx.y;           // feature 1/8th (64 floats)
    const int tid = threadIdx.x;
    const int fgrp = tid & 7;           // 8 floats each
    const int role = (tid >> 3) & 1;    // 0 = sum, 1 = max
    const int ctile = tid >> 4;         // 0..15
    const int f = y * 64 + fgrp * 8;
    const int len = lengths[b];
    const int ncc = (len < NCHUNK) ? len : NCHUNK;  // only written tiles

    float acc[8];
    #pragma unroll
    for (int i = 0; i < 8; ++i) acc[i] = role ? -INFINITY : 0.f;

    for (int c = ctile; c < ncc; c += 16) {
        const ushort* src = ws + ((size_t)b * NCHUNK + c) * (2 * F_DIM)
                               + role * F_DIM + f;
        ushort8v v = *reinterpret_cast<const ushort8v*>(src);
        if (role == 0) {
            #pragma unroll
            for (int i = 0; i < 8; ++i) acc[i] += bf16_val(v[i]);
        } else {
            #pragma unroll
            for (int i = 0; i < 8; ++i) acc[i] = fmaxf(acc[i], bf16_val(v[i]));
        }
    }

    __shared__ float red[16][2][8][8];   // [ctile][role][fgrp][i] = 16 KB
    #pragma unroll
    for (int i = 0; i < 8; ++i) red[ctile][role][fgrp][i] = acc[i];
    __syncthreads();

    #pragma unroll
    for (int h = 8; h >= 1; h >>= 1) {
        if (ctile < h) {
            if (role == 0) {
                #pragma unroll
                for (int i = 0; i < 8; ++i)
                    red[ctile][0][fgrp][i] += red[ctile + h][0][fgrp][i];
            } else {
                #pragma unroll
                for (int i = 0; i < 8; ++i)
                    red[ctile][1][fgrp][i] =
                        fmaxf(red[ctile][1][fgrp][i], red[ctile + h][1][fgrp][i]);
            }
        }
        __syncthreads();
    }

    if (ctile == 0) {
        float* ob = out + (size_t)b * (3 * F_DIM);
        if (role == 0) {
            const float inv = 1.0f / (float)len;
            float4 m0 = make_float4(red[0][0][fgrp][0] * inv, red[0][0][fgrp][1] * inv,
                                    red[0][0][fgrp][2] * inv, red[0][0][fgrp][3] * inv);
            float4 m1 = make_float4(red[0][0][fgrp][4] * inv, red[0][0][fgrp][5] * inv,
                                    red[0][0][fgrp][6] * inv, red[0][0][fgrp][7] * inv);
            *reinterpret_cast<float4*>(ob + F_DIM + f) = m0;
            *reinterpret_cast<float4*>(ob + F_DIM + f + 4) = m1;
        } else {
            float4 m0 = make_float4(red[0][1][fgrp][0], red[0][1][fgrp][1],
                                    red[0][1][fgrp][2], red[0][1][fgrp][3]);
            float4 m1 = make_float4(red[0][1][fgrp][4], red[0][1][fgrp][5],
                                    red[0][1][fgrp][6], red[0][1][fgrp][7]);
            *reinterpret_cast<float4*>(ob + 2 * F_DIM + f) = m0;
            *reinterpret_cast<float4*>(ob + 2 * F_DIM + f + 4) = m1;
        }
    }
}

extern "C" void kernel_launch(void* const* d_in, const int* in_sizes, int n_in,
                              void* d_out, int out_size, void* d_ws, size_t ws_size,
                              hipStream_t stream) {
    const float* x = (const float*)d_in[0];
    const int* lengths = (const int*)d_in[1];
    float* out = (float*)d_out;
    ushort* ws = (ushort*)d_ws;

    scp_partial<<<dim3(NCHUNK, B_DIM), 128, 0, stream>>>(x, lengths, ws, out);
    scp_finalize<<<dim3(B_DIM, 8), 256, 0, stream>>>(lengths, ws, out);
}